// Round 8
// baseline (403.030 us; speedup 1.0000x reference)
//
#include <hip/hip_runtime.h>
#include <math.h>

// GAT, N=4096, ~1% adjacency. fp16 end-to-end (R9). R13: LDS-staged packed
// lists (lgkm/vm split), 16 nodes/block. R15: v_fma_mix_f32 + x8 unroll
// (gather3 58.5us, plateau confirmed by R16 null). R17: pivot to GEMMs.
// gemm1/2 grids are 256 blocks = 1 block/CU = 1 wave/SIMD -> every K-step's
// vmcnt(0)+barrier drain fully exposed (no co-resident wave to overlap).
// GEMM block widened to 512 threads / 8 waves (2x4; 64x32 per wave, acc[4][2]),
// same 128x128 tile + verified swizzle; staging = exactly 1 GLL/thread/operand.
// Waves/SIMD doubles to 2 for gemm1/2; gathers reverted to R15 form.

#define N_NODES 4096
#define MAXNB 96
#define BM 128
#define BN 128
#define BK 32

typedef _Float16 f16x8 __attribute__((ext_vector_type(8)));
typedef float f32x4 __attribute__((ext_vector_type(4)));

#define GLL(gp, lp)                                                     \
  __builtin_amdgcn_global_load_lds(                                     \
      (const __attribute__((address_space(1))) void*)(gp),              \
      (__attribute__((address_space(3))) void*)(lp), 16, 0, 0)

// ---------------- fp16 helpers ----------------
union U16 {
  unsigned short u;
  _Float16 h;
};
__device__ __forceinline__ float h2f(unsigned short u) {
  U16 x;
  x.u = u;
  return (float)x.h;
}
__device__ __forceinline__ unsigned short f2h(float f) {
  U16 x;
  x.h = (_Float16)f;  // RNE
  return x.u;
}

// a += w * f16(lo/hi half of v) in ONE VALU op (VOP3P mixed-precision fma).
__device__ __forceinline__ void fmix_lo(float& a, float w, unsigned v) {
  asm("v_fma_mix_f32 %0, %1, %2, %0 op_sel:[0,0,0] op_sel_hi:[0,1,0]"
      : "+v"(a)
      : "v"(w), "v"(v));
}
__device__ __forceinline__ void fmix_hi(float& a, float w, unsigned v) {
  asm("v_fma_mix_f32 %0, %1, %2, %0 op_sel:[0,1,0] op_sel_hi:[0,1,0]"
      : "+v"(a)
      : "v"(w), "v"(v));
}

// ---------------- reduction helpers ----------------
__device__ __forceinline__ float wave_sum(float v) {
#pragma unroll
  for (int o = 32; o > 0; o >>= 1) v += __shfl_xor(v, o);
  return v;
}
__device__ __forceinline__ float wave_max(float v) {
#pragma unroll
  for (int o = 32; o > 0; o >>= 1) v = fmaxf(v, __shfl_xor(v, o));
  return v;
}
__device__ __forceinline__ float block_sum(float v, float* buf) {
  v = wave_sum(v);
  __syncthreads();
  if ((threadIdx.x & 63) == 0) buf[threadIdx.x >> 6] = v;
  __syncthreads();
  return buf[0] + buf[1] + buf[2] + buf[3];
}

// ---------------- zero f-buffers ----------------
__global__ __launch_bounds__(256) void zero_f(float* __restrict__ p, int n) {
  int i = blockIdx.x * 256 + threadIdx.x;
  if (i < n) p[i] = 0.f;
}

// ---------------- CSR build ----------------
__global__ __launch_bounds__(256) void build_csr(const float* __restrict__ adj,
                                                 int* __restrict__ cnt,
                                                 int* __restrict__ idx) {
  __shared__ int c;
  if (threadIdx.x == 0) c = 0;
  __syncthreads();
  const int row = blockIdx.x;
  const float* arow = adj + (size_t)row * N_NODES;
  for (int b = 0; b < N_NODES; b += 256) {
    float v = arow[b + threadIdx.x];
    if (v > 0.f) {
      int p = atomicAdd(&c, 1);
      if (p < MAXNB) idx[row * MAXNB + p] = b + threadIdx.x;
    }
  }
  __syncthreads();
  if (threadIdx.x == 0) cnt[row] = c < MAXNB ? c : MAXNB;
}

// ---------------- elementwise fp32 -> fp16 ----------------
__global__ __launch_bounds__(256) void convert_h(const float* __restrict__ in,
                                                 unsigned short* __restrict__ oh,
                                                 int n4) {
  int i = blockIdx.x * 256 + threadIdx.x;
  if (i >= n4) return;
  float4 v = ((const float4*)in)[i];
  ushort4 h;
  h.x = f2h(v.x);
  h.y = f2h(v.y);
  h.z = f2h(v.z);
  h.w = f2h(v.w);
  ((ushort4*)oh)[i] = h;
}

// ---------------- W [H][K][D] fp32 -> Bt [H*D][K] fp16 ----------------
__global__ __launch_bounds__(256) void convert_w(const float* __restrict__ W,
                                                 unsigned short* __restrict__ th,
                                                 int K, int D) {
  __shared__ float t[32][33];
  const int h = blockIdx.z;
  const int k0 = blockIdx.x * 32, d0 = blockIdx.y * 32;
  const int tx = threadIdx.x & 31, ty = threadIdx.x >> 5;
  const float* Wp = W + (size_t)h * K * D;
#pragma unroll
  for (int r = 0; r < 4; r++)
    t[ty + r * 8][tx] = Wp[(size_t)(k0 + ty + r * 8) * D + d0 + tx];
  __syncthreads();
#pragma unroll
  for (int r = 0; r < 4; r++) {
    int d = ty + r * 8;
    th[(size_t)(h * D + d0 + d) * K + k0 + tx] = f2h(t[tx][d]);
  }
}

// ---------------- fp16 MFMA GEMM: 128x128 tile, 512 thr / 8 waves (2x4) ----------------
// Cb[M][Ntot] (fp16) = A[M][K] @ Bt[Ntot][K]^T. Each wave: 64x32 via 4x2
// 16x16x32 frags. Staging: 1 GLL per thread per operand (512 x 16B = 8KB tile),
// same conflict-free swizzle: slot s holds chunk (s&3)^(((s>>2)>>1)&3) of row s>>2.
__global__ __launch_bounds__(512) void gemm_mfma(
    const unsigned short* __restrict__ A, const unsigned short* __restrict__ B,
    unsigned short* __restrict__ Cb, float* __restrict__ f1,
    float* __restrict__ f2, const float* __restrict__ af, int K, int Ntot, int D) {
  __shared__ unsigned short lds[2][2][BM * BK];  // 32 KB: [buf][A,B]

  const int tid = threadIdx.x;
  const int w = tid >> 6, lane = tid & 63;
  const int wm = w >> 2, wn = w & 3;
  const int quad = lane >> 4, l16 = lane & 15;
  const int m0 = blockIdx.x * BM, n0 = blockIdx.y * BN;

  const int s = tid;
  const int r = s >> 2, q = (s & 3) ^ ((r >> 1) & 3);
  const size_t offA = (size_t)(m0 + r) * K + q * 8;
  const size_t offB = (size_t)(n0 + r) * K + q * 8;

#define STAGE(b, k0)                             \
  do {                                           \
    GLL(A + offA + (k0), &lds[b][0][s * 8]);     \
    GLL(B + offB + (k0), &lds[b][1][s * 8]);     \
  } while (0)

  f32x4 acc[4][2];
#pragma unroll
  for (int i = 0; i < 4; i++)
#pragma unroll
    for (int j = 0; j < 2; j++) acc[i][j] = (f32x4){0.f, 0.f, 0.f, 0.f};

  // fragment read: row ra wants chunk `quad` -> stored at quad^((ra>>1)&3)
  int posA[4], posB[2];
#pragma unroll
  for (int i = 0; i < 4; i++) {
    int ra = wm * 64 + i * 16 + l16;
    posA[i] = (ra * 4 + (quad ^ ((ra >> 1) & 3))) * 8;
  }
#pragma unroll
  for (int j = 0; j < 2; j++) {
    int rb = wn * 32 + j * 16 + l16;
    posB[j] = (rb * 4 + (quad ^ ((rb >> 1) & 3))) * 8;
  }

  const int KT = K / BK;
  STAGE(0, 0);
  for (int kt = 0; kt < KT; kt++) {
    const int cur = kt & 1;
    __syncthreads();
    if (kt + 1 < KT) STAGE(cur ^ 1, (kt + 1) * BK);

    f16x8 fa[4], fb[2];
#pragma unroll
    for (int i = 0; i < 4; i++) fa[i] = *(const f16x8*)&lds[cur][0][posA[i]];
#pragma unroll
    for (int j = 0; j < 2; j++) fb[j] = *(const f16x8*)&lds[cur][1][posB[j]];
#pragma unroll
    for (int i = 0; i < 4; i++)
#pragma unroll
      for (int j = 0; j < 2; j++)
        acc[i][j] = __builtin_amdgcn_mfma_f32_16x16x32_f16(fa[i], fb[j],
                                                           acc[i][j], 0, 0, 0);
  }
#undef STAGE

  // epilogue 1: fp16 C write (C/D layout: col=l16, row=quad*4+r)
  const int gm = m0 + wm * 64 + quad * 4;
  const int gn = n0 + wn * 32 + l16;
#pragma unroll
  for (int i = 0; i < 4; i++)
#pragma unroll
    for (int j = 0; j < 2; j++) {
      unsigned short* p = Cb + (size_t)(gm + i * 16) * Ntot + gn + j * 16;
#pragma unroll
      for (int rr = 0; rr < 4; rr++) p[(size_t)rr * Ntot] = f2h(acc[i][j][rr]);
    }

  // epilogue 2: exact f1/f2 from fp32 acc (block spans one head: 128 | D)
  const int h = n0 / D;
  const int d0 = (n0 % D) + wn * 32 + l16;
  float a1v[2], a2v[2];
#pragma unroll
  for (int j = 0; j < 2; j++) {
    a1v[j] = af[h * 2 * D + d0 + j * 16];
    a2v[j] = af[h * 2 * D + D + d0 + j * 16];
  }
#pragma unroll
  for (int i = 0; i < 4; i++)
#pragma unroll
    for (int rr = 0; rr < 4; rr++) {
      float s1 = 0.f, s2 = 0.f;
#pragma unroll
      for (int j = 0; j < 2; j++) {
        s1 += acc[i][j][rr] * a1v[j];
        s2 += acc[i][j][rr] * a2v[j];
      }
#pragma unroll
      for (int m = 1; m < 16; m <<= 1) {
        s1 += __shfl_xor(s1, m);
        s2 += __shfl_xor(s2, m);
      }
      if (l16 == 0) {
        int row = gm + i * 16 + rr;
        atomicAdd(&f1[h * N_NODES + row], s1);
        atomicAdd(&f2[h * N_NODES + row], s2);
      }
    }
}

// ---------------- attention weights: 1 wave per (node, head), no barriers ----------------
// Writes packed {byteoff = nb*rowbytes, weight} int2 lists, zero-padded to the
// FULL MAXNB (pad entries {0, 0.f}) so gathers may over-read safely.
__global__ __launch_bounds__(256) void attw(const float* __restrict__ f1,
                                            const float* __restrict__ f2,
                                            const int* __restrict__ cnt,
                                            const int* __restrict__ idxs,
                                            int2* __restrict__ packed, int H,
                                            float scale, int rowbytes) {
  const int wid = blockIdx.x * 4 + (threadIdx.x >> 6);
  const int lane = threadIdx.x & 63;
  const int n = wid / H, h = wid - n * H;
  const int c = cnt[n];
  const float f1v = f1[h * N_NODES + n];
  // entry j0 = lane; entry j1 = lane + 64 (covers MAXNB=96)
  int nb0 = 0, nb1 = 0;
  float e0 = -3.0e38f, e1 = -3.0e38f;
  if (lane < c) {
    nb0 = idxs[n * MAXNB + lane];
    float s = f1v + f2[h * N_NODES + nb0];
    e0 = s >= 0.f ? s : 0.2f * s;
  }
  const int j1 = lane + 64;
  if (j1 < c) {
    nb1 = idxs[n * MAXNB + j1];
    float s = f1v + f2[h * N_NODES + nb1];
    e1 = s >= 0.f ? s : 0.2f * s;
  }
  float m = wave_max(fmaxf(e0, e1));
  float w0 = (lane < c) ? __expf(e0 - m) : 0.f;
  float w1 = (j1 < c) ? __expf(e1 - m) : 0.f;
  float inv = scale / wave_sum(w0 + w1);
  int2* pk = packed + (size_t)(h * N_NODES + n) * MAXNB;
  pk[lane] = make_int2(nb0 * rowbytes, __float_as_int(w0 * inv));
  if (j1 < MAXNB) pk[j1] = make_int2(nb1 * rowbytes, __float_as_int(w1 * inv));
}

// ---------------- layers 1&2 gather: 4 tiles x 256 cols (1 head each) ----------------
// Block = 16 nodes (4 per wave, sequential). Lists for the 16 nodes are one
// contiguous 12KB block -> staged to LDS with 3x 16B global_load_lds + one
// __syncthreads. List reads then hit lgkmcnt (independent of gather vmcnt).
__global__ __launch_bounds__(256) void gather12(
    const unsigned short* __restrict__ Whb, const int2* __restrict__ packed,
    const int* __restrict__ cnt, unsigned short* __restrict__ hh) {
  __shared__ int4 sl[16][MAXNB / 2];  // 12 KB
  const int t = blockIdx.x & 3;  // tile == head (256 cols)
  const int g = blockIdx.x >> 2;
  const int tid = threadIdx.x, w = tid >> 6, lane = tid & 63;
  const int nbase = g * 16;
  const char* src = (const char*)(packed + (size_t)(t * N_NODES + nbase) * MAXNB);
#pragma unroll
  for (int p = 0; p < 3; p++)
    GLL(src + p * 4096 + tid * 16, (char*)sl + p * 4096 + tid * 16);

  const int nb0 = nbase + w * 4;
  const int4 cv = *(const int4*)(cnt + nb0);
  const int ca[4] = {cv.x, cv.y, cv.z, cv.w};
  const char* wb = (const char*)Whb;
  const unsigned colb = (unsigned)(t * 256 + lane * 4) * 2u;  // 8 B per lane
  __syncthreads();

#pragma unroll
  for (int k = 0; k < 4; k++) {
    const int n = nb0 + k;
    const int c4 = (ca[k] + 3) & ~3;
    const int4* __restrict__ sb = sl[w * 4 + k];
    float a0 = 0.f, a1 = 0.f, a2 = 0.f, a3 = 0.f;
    for (int j = 0; j < c4; j += 4) {
      int4 e0 = sb[j >> 1];
      int4 e1 = sb[(j >> 1) + 1];
      uint2 v0 = *(const uint2*)(wb + (unsigned)e0.x + colb);
      uint2 v1 = *(const uint2*)(wb + (unsigned)e0.z + colb);
      uint2 v2 = *(const uint2*)(wb + (unsigned)e1.x + colb);
      uint2 v3 = *(const uint2*)(wb + (unsigned)e1.z + colb);
      float w0 = __int_as_float(e0.y), w1 = __int_as_float(e0.w);
      float w2 = __int_as_float(e1.y), w3 = __int_as_float(e1.w);
      fmix_lo(a0, w0, v0.x); fmix_hi(a1, w0, v0.x);
      fmix_lo(a2, w0, v0.y); fmix_hi(a3, w0, v0.y);
      fmix_lo(a0, w1, v1.x); fmix_hi(a1, w1, v1.x);
      fmix_lo(a2, w1, v1.y); fmix_hi(a3, w1, v1.y);
      fmix_lo(a0, w2, v2.x); fmix_hi(a1, w2, v2.x);
      fmix_lo(a2, w2, v2.y); fmix_hi(a3, w2, v2.y);
      fmix_lo(a0, w3, v3.x); fmix_hi(a1, w3, v3.x);
      fmix_lo(a2, w3, v3.y); fmix_hi(a3, w3, v3.y);
    }
    float o[4] = {a0, a1, a2, a3};
    unsigned short oh[4];
#pragma unroll
    for (int s = 0; s < 4; s++) {
      float v = o[s];
      v = v > 0.f ? v : __expf(v) - 1.f;  // elu (per-head)
      v = v > 0.f ? v : __expf(v) - 1.f;  // elu (post-concat)
      oh[s] = f2h(v);
    }
    uint2 ov;
    ov.x = (unsigned)oh[0] | ((unsigned)oh[1] << 16);
    ov.y = (unsigned)oh[2] | ((unsigned)oh[3] << 16);
    *(uint2*)(hh + (size_t)n * 1024 + t * 256 + lane * 4) = ov;
  }
}

// ---------------- layer 3 gather: 24 tiles x 128 cols (XCD-balanced) ----------------
// Full wave per node, 4 B/lane, unrolled x8 (8 loads in flight per wave).
__global__ __launch_bounds__(256) void gather3(
    const unsigned short* __restrict__ Whb, const int2* __restrict__ packed,
    const int* __restrict__ cnt, unsigned short* __restrict__ aggb) {
  __shared__ int4 sl[16][MAXNB / 2];  // 12 KB
  const int t = blockIdx.x % 24;
  const int g = blockIdx.x / 24;
  const int tid = threadIdx.x, w = tid >> 6, lane = tid & 63;
  const int h = t >> 2;  // 4 tiles per head (D=512)
  const int nbase = g * 16;
  const char* src = (const char*)(packed + (size_t)(h * N_NODES + nbase) * MAXNB);
#pragma unroll
  for (int p = 0; p < 3; p++)
    GLL(src + p * 4096 + tid * 16, (char*)sl + p * 4096 + tid * 16);

  const int nb0 = nbase + w * 4;
  const int4 cv = *(const int4*)(cnt + nb0);
  const int ca[4] = {cv.x, cv.y, cv.z, cv.w};
  const char* wb = (const char*)Whb;
  const unsigned colb = (unsigned)(t * 128 + lane * 2) * 2u;  // 4 B per lane
  const int cc = t * 128 - h * 512 + lane * 2;                // col within head
  __syncthreads();

#pragma unroll
  for (int k = 0; k < 4; k++) {
    const int n = nb0 + k;
    const int c8 = (ca[k] + 7) & ~7;
    const int4* __restrict__ sb = sl[w * 4 + k];
    float a0 = 0.f, a1 = 0.f;
    for (int j = 0; j < c8; j += 8) {
      int4 e01 = sb[j >> 1];
      int4 e23 = sb[(j >> 1) + 1];
      int4 e45 = sb[(j >> 1) + 2];
      int4 e67 = sb[(j >> 1) + 3];
      unsigned v0 = *(const unsigned*)(wb + (unsigned)e01.x + colb);
      unsigned v1 = *(const unsigned*)(wb + (unsigned)e01.z + colb);
      unsigned v2 = *(const unsigned*)(wb + (unsigned)e23.x + colb);
      unsigned v3 = *(const unsigned*)(wb + (unsigned)e23.z + colb);
      unsigned v4 = *(const unsigned*)(wb + (unsigned)e45.x + colb);
      unsigned v5 = *(const unsigned*)(wb + (unsigned)e45.z + colb);
      unsigned v6 = *(const unsigned*)(wb + (unsigned)e67.x + colb);
      unsigned v7 = *(const unsigned*)(wb + (unsigned)e67.z + colb);
      float w0 = __int_as_float(e01.y), w1 = __int_as_float(e01.w);
      float w2 = __int_as_float(e23.y), w3 = __int_as_float(e23.w);
      float w4 = __int_as_float(e45.y), w5 = __int_as_float(e45.w);
      float w6 = __int_as_float(e67.y), w7 = __int_as_float(e67.w);
      fmix_lo(a0, w0, v0); fmix_hi(a1, w0, v0);
      fmix_lo(a0, w1, v1); fmix_hi(a1, w1, v1);
      fmix_lo(a0, w2, v2); fmix_hi(a1, w2, v2);
      fmix_lo(a0, w3, v3); fmix_hi(a1, w3, v3);
      fmix_lo(a0, w4, v4); fmix_hi(a1, w4, v4);
      fmix_lo(a0, w5, v5); fmix_hi(a1, w5, v5);
      fmix_lo(a0, w6, v6); fmix_hi(a1, w6, v6);
      fmix_lo(a0, w7, v7); fmix_hi(a1, w7, v7);
    }
    unsigned ov = (unsigned)f2h(a0) | ((unsigned)f2h(a1) << 16);
    *(unsigned*)(aggb + ((size_t)h * N_NODES + n) * 512 + cc) = ov;
  }
}

// ---------------- layer 3 reduce: head-sum + elu + L2-normalize ----------------
__global__ __launch_bounds__(256) void reduce3(const unsigned short* __restrict__ aggb,
                                               float* __restrict__ out) {
  __shared__ float buf[4];
  const int n = blockIdx.x, tid = threadIdx.x;
  float v0 = 0.f, v1 = 0.f;
#pragma unroll
  for (int h = 0; h < 6; h++) {
    ushort2 u = *(const ushort2*)(aggb + ((size_t)h * N_NODES + n) * 512 + tid * 2);
    v0 += h2f(u.x);
    v1 += h2f(u.y);
  }
  v0 = v0 > 0.f ? v0 : __expf(v0) - 1.f;
  v1 = v1 > 0.f ? v1 : __expf(v1) - 1.f;
  float ss = block_sum(v0 * v0 + v1 * v1, buf);
  float inv = 1.f / fmaxf(sqrtf(ss), 1e-12f);
  out[(size_t)n * 512 + tid * 2] = v0 * inv;
  out[(size_t)n * 512 + tid * 2 + 1] = v1 * inv;
}

extern "C" void kernel_launch(void* const* d_in, const int* in_sizes, int n_in,
                              void* d_out, int out_size, void* d_ws, size_t ws_size,
                              hipStream_t stream) {
  (void)in_sizes; (void)n_in; (void)out_size; (void)ws_size;
  const float* x   = (const float*)d_in[0];  // [4096, 2048]
  const float* adj = (const float*)d_in[1];  // [4096, 4096]
  const float* W1  = (const float*)d_in[2];  // [4, 2048, 256]
  const float* a1  = (const float*)d_in[3];  // [4, 512]
  const float* W2  = (const float*)d_in[4];  // [4, 1024, 256]
  const float* a2  = (const float*)d_in[5];  // [4, 512]
  const float* W3  = (const float*)d_in[6];  // [6, 1024, 512]
  const float* a3  = (const float*)d_in[7];  // [6, 1024]
  float* out = (float*)d_out;                // [4096, 512]

  // workspace layout (~75 MB peak)
  char* ws = (char*)d_ws;
  size_t off = 0;
  auto alloc = [&](size_t bytes) {
    void* p = ws + off;
    off += (bytes + 255) & ~(size_t)255;
    return p;
  };
  int* nbr_cnt = (int*)alloc((size_t)N_NODES * 4);
  int* nbr_idx = (int*)alloc((size_t)N_NODES * MAXNB * 4);               // 1.6 MB
  float* fbuf = (float*)alloc((size_t)28 * N_NODES * 4);
  unsigned short* Wt = (unsigned short*)alloc((size_t)6 * 1024 * 512 * 2);  // 6.3 MB
  unsigned short* Areg = (unsigned short*)alloc((size_t)N_NODES * 2048 * 2);  // 16.8 MB
  unsigned short* Whb = (unsigned short*)alloc((size_t)N_NODES * 3072 * 2);   // 25.2 MB
  unsigned short* aggb = (unsigned short*)alloc((size_t)6 * N_NODES * 512 * 2);  // 25.2 MB

  // overlays:
  //  xh       = Areg (16.8 MB, dead after gemm1)
  //  hh       = Areg second half (written by gather12, read by gemm2/gemm3)
  //  packed12 = aggb (12.6 MB; aggb not live until gather3)
  //  packed3  = Wt..Areg (18.9 MB <= 23.1 MB; both dead after gemm3; attw3 only
  //             reads fbuf/nbr_idx which precede Wt)
  unsigned short* xh = Areg;
  unsigned short* hh = Areg + (size_t)N_NODES * 1024;
  int2* packed12 = (int2*)aggb;
  int2* packed3 = (int2*)Wt;

  float* f1_1 = fbuf;
  float* f2_1 = fbuf + 4 * N_NODES;
  float* f1_2 = fbuf + 8 * N_NODES;
  float* f2_2 = fbuf + 12 * N_NODES;
  float* f1_3 = fbuf + 16 * N_NODES;
  float* f2_3 = fbuf + 22 * N_NODES;

  zero_f<<<(28 * N_NODES + 255) / 256, 256, 0, stream>>>(fbuf, 28 * N_NODES);
  build_csr<<<N_NODES, 256, 0, stream>>>(adj, nbr_cnt, nbr_idx);

  // ---- layer 1: A = x (K=2048), Ntot = 1024, D = 256 ----
  convert_h<<<(N_NODES * 2048 / 4 + 255) / 256, 256, 0, stream>>>(
      x, xh, N_NODES * 2048 / 4);
  convert_w<<<dim3(2048 / 32, 256 / 32, 4), 256, 0, stream>>>(W1, Wt, 2048, 256);
  gemm_mfma<<<dim3(N_NODES / BM, 1024 / BN), 512, 0, stream>>>(
      xh, Wt, Whb, f1_1, f2_1, a1, 2048, 1024, 256);
  attw<<<N_NODES * 4 / 4, 256, 0, stream>>>(f1_1, f2_1, nbr_cnt, nbr_idx,
                                            packed12, 4, 1.f, 2048);
  gather12<<<4 * (N_NODES / 16), 256, 0, stream>>>(Whb, packed12, nbr_cnt, hh);

  // ---- layer 2: A = h (K=1024), Ntot = 1024, D = 256 ----
  convert_w<<<dim3(1024 / 32, 256 / 32, 4), 256, 0, stream>>>(W2, Wt, 1024, 256);
  gemm_mfma<<<dim3(N_NODES / BM, 1024 / BN), 512, 0, stream>>>(
      hh, Wt, Whb, f1_2, f2_2, a2, 1024, 1024, 256);
  attw<<<N_NODES * 4 / 4, 256, 0, stream>>>(f1_2, f2_2, nbr_cnt, nbr_idx,
                                            packed12, 4, 1.f, 2048);
  gather12<<<4 * (N_NODES / 16), 256, 0, stream>>>(Whb, packed12, nbr_cnt, hh);

  // ---- layer 3: A = h (K=1024), Ntot = 3072, D = 512 ----
  convert_w<<<dim3(1024 / 32, 512 / 32, 6), 256, 0, stream>>>(W3, Wt, 1024, 512);
  gemm_mfma<<<dim3(N_NODES / BM, 3072 / BN), 512, 0, stream>>>(
      hh, Wt, Whb, f1_3, f2_3, a3, 1024, 3072, 512);
  attw<<<N_NODES * 6 / 4, 256, 0, stream>>>(f1_3, f2_3, nbr_cnt, nbr_idx,
                                            packed3, 6, 1.f / 6.f, 6144);
  gather3<<<24 * (N_NODES / 16), 256, 0, stream>>>(Whb, packed3, nbr_cnt, aggb);
  reduce3<<<N_NODES, 256, 0, stream>>>(aggb, out);
}

// Round 10
// 395.223 us; speedup vs baseline: 1.0198x; 1.0198x over previous
//
#include <hip/hip_runtime.h>
#include <math.h>

// GAT, N=4096, ~1% adjacency. fp16 end-to-end (R9). R13: LDS-staged packed
// lists (lgkm/vm split). R15: v_fma_mix_f32 + x8 unroll (gather3 57.5-58.5us;
// R16 interleave null -> gather plateau; R17 512-thr GEMM null -> reverted).
// R18 (fixed R19: local f1h/f2h renamed f1p/f2p -- was shadowing f2h()):
// (1) attw FUSED into gather12 (tile==head, so no duplication): idx read
// coalesced from global, f2 head-slab (16KB) L1-hot, packed {byteoff,weight}
// list written straight to LDS by the owning wave -- kills 2 attw launches +
// 25MB packed12 round trip + gather12's GLL staging, zero barriers
// (wave-private lists). (2) zero_f fused into build_csr. (3) attw3+gather3
// unchanged (4 tiles/head would duplicate attw x4).

#define N_NODES 4096
#define MAXNB 96
#define BM 128
#define BN 128
#define BK 32

typedef _Float16 f16x8 __attribute__((ext_vector_type(8)));
typedef float f32x4 __attribute__((ext_vector_type(4)));

#define GLL(gp, lp)                                                     \
  __builtin_amdgcn_global_load_lds(                                     \
      (const __attribute__((address_space(1))) void*)(gp),              \
      (__attribute__((address_space(3))) void*)(lp), 16, 0, 0)

// ---------------- fp16 helpers ----------------
union U16 {
  unsigned short u;
  _Float16 h;
};
__device__ __forceinline__ float h2f(unsigned short u) {
  U16 x;
  x.u = u;
  return (float)x.h;
}
__device__ __forceinline__ unsigned short f2h(float f) {
  U16 x;
  x.h = (_Float16)f;  // RNE
  return x.u;
}

// a += w * f16(lo/hi half of v) in ONE VALU op (VOP3P mixed-precision fma).
__device__ __forceinline__ void fmix_lo(float& a, float w, unsigned v) {
  asm("v_fma_mix_f32 %0, %1, %2, %0 op_sel:[0,0,0] op_sel_hi:[0,1,0]"
      : "+v"(a)
      : "v"(w), "v"(v));
}
__device__ __forceinline__ void fmix_hi(float& a, float w, unsigned v) {
  asm("v_fma_mix_f32 %0, %1, %2, %0 op_sel:[0,1,0] op_sel_hi:[0,1,0]"
      : "+v"(a)
      : "v"(w), "v"(v));
}

// ---------------- reduction helpers ----------------
__device__ __forceinline__ float wave_sum(float v) {
#pragma unroll
  for (int o = 32; o > 0; o >>= 1) v += __shfl_xor(v, o);
  return v;
}
__device__ __forceinline__ float wave_max(float v) {
#pragma unroll
  for (int o = 32; o > 0; o >>= 1) v = fmaxf(v, __shfl_xor(v, o));
  return v;
}
__device__ __forceinline__ float block_sum(float v, float* buf) {
  v = wave_sum(v);
  __syncthreads();
  if ((threadIdx.x & 63) == 0) buf[threadIdx.x >> 6] = v;
  __syncthreads();
  return buf[0] + buf[1] + buf[2] + buf[3];
}

// ---------------- CSR build (+ fused fbuf zero) ----------------
__global__ __launch_bounds__(256) void build_csr(const float* __restrict__ adj,
                                                 int* __restrict__ cnt,
                                                 int* __restrict__ idx,
                                                 float* __restrict__ fbuf) {
  __shared__ int c;
  if (threadIdx.x == 0) c = 0;
  if (threadIdx.x < 28) fbuf[threadIdx.x * N_NODES + blockIdx.x] = 0.f;
  __syncthreads();
  const int row = blockIdx.x;
  const float* arow = adj + (size_t)row * N_NODES;
  for (int b = 0; b < N_NODES; b += 256) {
    float v = arow[b + threadIdx.x];
    if (v > 0.f) {
      int p = atomicAdd(&c, 1);
      if (p < MAXNB) idx[row * MAXNB + p] = b + threadIdx.x;
    }
  }
  __syncthreads();
  if (threadIdx.x == 0) cnt[row] = c < MAXNB ? c : MAXNB;
}

// ---------------- elementwise fp32 -> fp16 ----------------
__global__ __launch_bounds__(256) void convert_h(const float* __restrict__ in,
                                                 unsigned short* __restrict__ oh,
                                                 int n4) {
  int i = blockIdx.x * 256 + threadIdx.x;
  if (i >= n4) return;
  float4 v = ((const float4*)in)[i];
  ushort4 h;
  h.x = f2h(v.x);
  h.y = f2h(v.y);
  h.z = f2h(v.z);
  h.w = f2h(v.w);
  ((ushort4*)oh)[i] = h;
}

// ---------------- W [H][K][D] fp32 -> Bt [H*D][K] fp16 ----------------
__global__ __launch_bounds__(256) void convert_w(const float* __restrict__ W,
                                                 unsigned short* __restrict__ th,
                                                 int K, int D) {
  __shared__ float t[32][33];
  const int h = blockIdx.z;
  const int k0 = blockIdx.x * 32, d0 = blockIdx.y * 32;
  const int tx = threadIdx.x & 31, ty = threadIdx.x >> 5;
  const float* Wp = W + (size_t)h * K * D;
#pragma unroll
  for (int r = 0; r < 4; r++)
    t[ty + r * 8][tx] = Wp[(size_t)(k0 + ty + r * 8) * D + d0 + tx];
  __syncthreads();
#pragma unroll
  for (int r = 0; r < 4; r++) {
    int d = ty + r * 8;
    th[(size_t)(h * D + d0 + d) * K + k0 + tx] = f2h(t[tx][d]);
  }
}

// ---------------- fp16 MFMA GEMM: 128x128 tile, dbuf, conflict-free swizzle ----------------
__global__ __launch_bounds__(256) void gemm_mfma(
    const unsigned short* __restrict__ A, const unsigned short* __restrict__ B,
    unsigned short* __restrict__ Cb, float* __restrict__ f1,
    float* __restrict__ f2, const float* __restrict__ af, int K, int Ntot, int D) {
  __shared__ unsigned short lds[2][2][BM * BK];  // 32 KB: [buf][A,B]

  const int tid = threadIdx.x;
  const int w = tid >> 6, lane = tid & 63;
  const int wm = w >> 1, wn = w & 1;
  const int quad = lane >> 4, l16 = lane & 15;
  const int m0 = blockIdx.x * BM, n0 = blockIdx.y * BN;

  const int s0 = w * 128 + lane, s1 = s0 + 64;
  const int r0 = s0 >> 2, q0 = (s0 & 3) ^ ((r0 >> 1) & 3);
  const int r1 = s1 >> 2, q1 = (s1 & 3) ^ ((r1 >> 1) & 3);
  const size_t offA0 = (size_t)(m0 + r0) * K + q0 * 8;
  const size_t offA1 = (size_t)(m0 + r1) * K + q1 * 8;
  const size_t offB0 = (size_t)(n0 + r0) * K + q0 * 8;
  const size_t offB1 = (size_t)(n0 + r1) * K + q1 * 8;

#define STAGE(b, k0)                                \
  do {                                              \
    GLL(A + offA0 + (k0), &lds[b][0][s0 * 8]);      \
    GLL(A + offA1 + (k0), &lds[b][0][s1 * 8]);      \
    GLL(B + offB0 + (k0), &lds[b][1][s0 * 8]);      \
    GLL(B + offB1 + (k0), &lds[b][1][s1 * 8]);      \
  } while (0)

  f32x4 acc[4][4];
#pragma unroll
  for (int i = 0; i < 4; i++)
#pragma unroll
    for (int j = 0; j < 4; j++) acc[i][j] = (f32x4){0.f, 0.f, 0.f, 0.f};

  int posA[4], posB[4];
#pragma unroll
  for (int i = 0; i < 4; i++) {
    int ra = wm * 64 + i * 16 + l16;
    posA[i] = (ra * 4 + (quad ^ ((ra >> 1) & 3))) * 8;
    int rb = wn * 64 + i * 16 + l16;
    posB[i] = (rb * 4 + (quad ^ ((rb >> 1) & 3))) * 8;
  }

  const int KT = K / BK;
  STAGE(0, 0);
  for (int kt = 0; kt < KT; kt++) {
    const int cur = kt & 1;
    __syncthreads();
    if (kt + 1 < KT) STAGE(cur ^ 1, (kt + 1) * BK);

    f16x8 fa[4], fb[4];
#pragma unroll
    for (int i = 0; i < 4; i++) {
      fa[i] = *(const f16x8*)&lds[cur][0][posA[i]];
      fb[i] = *(const f16x8*)&lds[cur][1][posB[i]];
    }
#pragma unroll
    for (int i = 0; i < 4; i++)
#pragma unroll
      for (int j = 0; j < 4; j++)
        acc[i][j] = __builtin_amdgcn_mfma_f32_16x16x32_f16(fa[i], fb[j],
                                                           acc[i][j], 0, 0, 0);
  }
#undef STAGE

  // epilogue 1: fp16 C write (C/D layout: col=l16, row=quad*4+r)
  const int gm = m0 + wm * 64 + quad * 4;
  const int gn = n0 + wn * 64 + l16;
#pragma unroll
  for (int i = 0; i < 4; i++)
#pragma unroll
    for (int j = 0; j < 4; j++) {
      unsigned short* p = Cb + (size_t)(gm + i * 16) * Ntot + gn + j * 16;
#pragma unroll
      for (int r = 0; r < 4; r++) p[(size_t)r * Ntot] = f2h(acc[i][j][r]);
    }

  // epilogue 2: exact f1/f2 from fp32 acc (block spans one head: 128 | D)
  const int h = n0 / D;
  const int d0 = (n0 % D) + wn * 64 + l16;
  float a1v[4], a2v[4];
#pragma unroll
  for (int j = 0; j < 4; j++) {
    a1v[j] = af[h * 2 * D + d0 + j * 16];
    a2v[j] = af[h * 2 * D + D + d0 + j * 16];
  }
#pragma unroll
  for (int i = 0; i < 4; i++)
#pragma unroll
    for (int r = 0; r < 4; r++) {
      float s1 = 0.f, s2 = 0.f;
#pragma unroll
      for (int j = 0; j < 4; j++) {
        s1 += acc[i][j][r] * a1v[j];
        s2 += acc[i][j][r] * a2v[j];
      }
#pragma unroll
      for (int m = 1; m < 16; m <<= 1) {
        s1 += __shfl_xor(s1, m);
        s2 += __shfl_xor(s2, m);
      }
      if (l16 == 0) {
        int row = gm + i * 16 + r;
        atomicAdd(&f1[h * N_NODES + row], s1);
        atomicAdd(&f2[h * N_NODES + row], s2);
      }
    }
}

// ---------------- attention weights (layer 3 only): 1 wave per (node, head) ----------------
// Writes packed {byteoff = nb*rowbytes, weight} int2 lists, zero-padded to the
// FULL MAXNB (pad entries {0, 0.f}) so gathers may over-read safely.
__global__ __launch_bounds__(256) void attw(const float* __restrict__ f1,
                                            const float* __restrict__ f2,
                                            const int* __restrict__ cnt,
                                            const int* __restrict__ idxs,
                                            int2* __restrict__ packed, int H,
                                            float scale, int rowbytes) {
  const int wid = blockIdx.x * 4 + (threadIdx.x >> 6);
  const int lane = threadIdx.x & 63;
  const int n = wid / H, h = wid - n * H;
  const int c = cnt[n];
  const float f1v = f1[h * N_NODES + n];
  int nb0 = 0, nb1 = 0;
  float e0 = -3.0e38f, e1 = -3.0e38f;
  if (lane < c) {
    nb0 = idxs[n * MAXNB + lane];
    float s = f1v + f2[h * N_NODES + nb0];
    e0 = s >= 0.f ? s : 0.2f * s;
  }
  const int j1 = lane + 64;
  if (j1 < c) {
    nb1 = idxs[n * MAXNB + j1];
    float s = f1v + f2[h * N_NODES + nb1];
    e1 = s >= 0.f ? s : 0.2f * s;
  }
  float m = wave_max(fmaxf(e0, e1));
  float w0 = (lane < c) ? __expf(e0 - m) : 0.f;
  float w1 = (j1 < c) ? __expf(e1 - m) : 0.f;
  float inv = scale / wave_sum(w0 + w1);
  int2* pk = packed + (size_t)(h * N_NODES + n) * MAXNB;
  pk[lane] = make_int2(nb0 * rowbytes, __float_as_int(w0 * inv));
  if (j1 < MAXNB) pk[j1] = make_int2(nb1 * rowbytes, __float_as_int(w1 * inv));
}

// ---------------- layers 1&2 FUSED attw+gather: 4 tiles x 256 cols ----------------
// Block = 16 nodes (4 per wave). Phase 1: each wave computes softmax weights
// for its 4 nodes (idx coalesced from global, f2 head-slab L1-hot, shuffle
// reductions) and writes packed {byteoff, weight} lists into ITS OWN LDS rows.
// Phase 2: R15 gather inner loop (ds_read b128 + fmix). No barriers at all.
__global__ __launch_bounds__(256) void fgather12(
    const unsigned short* __restrict__ Whb, const float* __restrict__ f1,
    const float* __restrict__ f2, const int* __restrict__ cnt,
    const int* __restrict__ idxs, unsigned short* __restrict__ hh) {
  __shared__ int2 sl[16][MAXNB];  // 12 KB
  const int t = blockIdx.x & 3;  // tile == head (256 cols)
  const int g = blockIdx.x >> 2;
  const int tid = threadIdx.x, w = tid >> 6, lane = tid & 63;
  const int nbase = g * 16 + w * 4;
  const int4 cv = *(const int4*)(cnt + nbase);
  const int ca[4] = {cv.x, cv.y, cv.z, cv.w};
  const float* __restrict__ f1p = f1 + t * N_NODES;
  const float* __restrict__ f2p = f2 + t * N_NODES;

  // phase 1: attention weights -> LDS packed lists (wave-private rows)
#pragma unroll
  for (int k = 0; k < 4; k++) {
    const int n = nbase + k;
    const int c = ca[k];
    const float f1v = f1p[n];
    int nb0 = 0, nb1 = 0;
    float e0 = -3.0e38f, e1 = -3.0e38f;
    if (lane < c) {
      nb0 = idxs[n * MAXNB + lane];
      float s = f1v + f2p[nb0];
      e0 = s >= 0.f ? s : 0.2f * s;
    }
    const int j1 = lane + 64;
    if (j1 < c) {
      nb1 = idxs[n * MAXNB + j1];
      float s = f1v + f2p[nb1];
      e1 = s >= 0.f ? s : 0.2f * s;
    }
    float m = wave_max(fmaxf(e0, e1));
    float w0 = (lane < c) ? __expf(e0 - m) : 0.f;
    float w1 = (j1 < c) ? __expf(e1 - m) : 0.f;
    float inv = 1.f / wave_sum(w0 + w1);
    sl[w * 4 + k][lane] = make_int2(nb0 * 2048, __float_as_int(w0 * inv));
    if (lane < MAXNB - 64)
      sl[w * 4 + k][j1] = make_int2(nb1 * 2048, __float_as_int(w1 * inv));
  }

  // phase 2: gather
  const char* wb = (const char*)Whb;
  const unsigned colb = (unsigned)(t * 256 + lane * 4) * 2u;  // 8 B per lane
#pragma unroll
  for (int k = 0; k < 4; k++) {
    const int n = nbase + k;
    const int c4 = (ca[k] + 3) & ~3;
    const int4* __restrict__ sb = (const int4*)&sl[w * 4 + k][0];
    float a0 = 0.f, a1 = 0.f, a2 = 0.f, a3 = 0.f;
    for (int j = 0; j < c4; j += 4) {
      int4 e0 = sb[j >> 1];
      int4 e1 = sb[(j >> 1) + 1];
      uint2 v0 = *(const uint2*)(wb + (unsigned)e0.x + colb);
      uint2 v1 = *(const uint2*)(wb + (unsigned)e0.z + colb);
      uint2 v2 = *(const uint2*)(wb + (unsigned)e1.x + colb);
      uint2 v3 = *(const uint2*)(wb + (unsigned)e1.z + colb);
      float w0 = __int_as_float(e0.y), w1 = __int_as_float(e0.w);
      float w2 = __int_as_float(e1.y), w3 = __int_as_float(e1.w);
      fmix_lo(a0, w0, v0.x); fmix_hi(a1, w0, v0.x);
      fmix_lo(a2, w0, v0.y); fmix_hi(a3, w0, v0.y);
      fmix_lo(a0, w1, v1.x); fmix_hi(a1, w1, v1.x);
      fmix_lo(a2, w1, v1.y); fmix_hi(a3, w1, v1.y);
      fmix_lo(a0, w2, v2.x); fmix_hi(a1, w2, v2.x);
      fmix_lo(a2, w2, v2.y); fmix_hi(a3, w2, v2.y);
      fmix_lo(a0, w3, v3.x); fmix_hi(a1, w3, v3.x);
      fmix_lo(a2, w3, v3.y); fmix_hi(a3, w3, v3.y);
    }
    float o[4] = {a0, a1, a2, a3};
    unsigned short oh[4];
#pragma unroll
    for (int s = 0; s < 4; s++) {
      float v = o[s];
      v = v > 0.f ? v : __expf(v) - 1.f;  // elu (per-head)
      v = v > 0.f ? v : __expf(v) - 1.f;  // elu (post-concat)
      oh[s] = f2h(v);
    }
    uint2 ov;
    ov.x = (unsigned)oh[0] | ((unsigned)oh[1] << 16);
    ov.y = (unsigned)oh[2] | ((unsigned)oh[3] << 16);
    *(uint2*)(hh + (size_t)n * 1024 + t * 256 + lane * 4) = ov;
  }
}

// ---------------- layer 3 gather: 24 tiles x 128 cols (XCD-balanced) ----------------
// Full wave per node, 4 B/lane, unrolled x8 (8 loads in flight per wave).
__global__ __launch_bounds__(256) void gather3(
    const unsigned short* __restrict__ Whb, const int2* __restrict__ packed,
    const int* __restrict__ cnt, unsigned short* __restrict__ aggb) {
  __shared__ int4 sl[16][MAXNB / 2];  // 12 KB
  const int t = blockIdx.x % 24;
  const int g = blockIdx.x / 24;
  const int tid = threadIdx.x, w = tid >> 6, lane = tid & 63;
  const int h = t >> 2;  // 4 tiles per head (D=512)
  const int nbase = g * 16;
  const char* src = (const char*)(packed + (size_t)(h * N_NODES + nbase) * MAXNB);
#pragma unroll
  for (int p = 0; p < 3; p++)
    GLL(src + p * 4096 + tid * 16, (char*)sl + p * 4096 + tid * 16);

  const int nb0 = nbase + w * 4;
  const int4 cv = *(const int4*)(cnt + nb0);
  const int ca[4] = {cv.x, cv.y, cv.z, cv.w};
  const char* wb = (const char*)Whb;
  const unsigned colb = (unsigned)(t * 128 + lane * 2) * 2u;  // 4 B per lane
  const int cc = t * 128 - h * 512 + lane * 2;                // col within head
  __syncthreads();

#pragma unroll
  for (int k = 0; k < 4; k++) {
    const int n = nb0 + k;
    const int c8 = (ca[k] + 7) & ~7;
    const int4* __restrict__ sb = sl[w * 4 + k];
    float a0 = 0.f, a1 = 0.f;
    for (int j = 0; j < c8; j += 8) {
      int4 e01 = sb[j >> 1];
      int4 e23 = sb[(j >> 1) + 1];
      int4 e45 = sb[(j >> 1) + 2];
      int4 e67 = sb[(j >> 1) + 3];
      unsigned v0 = *(const unsigned*)(wb + (unsigned)e01.x + colb);
      unsigned v1 = *(const unsigned*)(wb + (unsigned)e01.z + colb);
      unsigned v2 = *(const unsigned*)(wb + (unsigned)e23.x + colb);
      unsigned v3 = *(const unsigned*)(wb + (unsigned)e23.z + colb);
      unsigned v4 = *(const unsigned*)(wb + (unsigned)e45.x + colb);
      unsigned v5 = *(const unsigned*)(wb + (unsigned)e45.z + colb);
      unsigned v6 = *(const unsigned*)(wb + (unsigned)e67.x + colb);
      unsigned v7 = *(const unsigned*)(wb + (unsigned)e67.z + colb);
      float w0 = __int_as_float(e01.y), w1 = __int_as_float(e01.w);
      float w2 = __int_as_float(e23.y), w3 = __int_as_float(e23.w);
      float w4 = __int_as_float(e45.y), w5 = __int_as_float(e45.w);
      float w6 = __int_as_float(e67.y), w7 = __int_as_float(e67.w);
      fmix_lo(a0, w0, v0); fmix_hi(a1, w0, v0);
      fmix_lo(a0, w1, v1); fmix_hi(a1, w1, v1);
      fmix_lo(a0, w2, v2); fmix_hi(a1, w2, v2);
      fmix_lo(a0, w3, v3); fmix_hi(a1, w3, v3);
      fmix_lo(a0, w4, v4); fmix_hi(a1, w4, v4);
      fmix_lo(a0, w5, v5); fmix_hi(a1, w5, v5);
      fmix_lo(a0, w6, v6); fmix_hi(a1, w6, v6);
      fmix_lo(a0, w7, v7); fmix_hi(a1, w7, v7);
    }
    unsigned ov = (unsigned)f2h(a0) | ((unsigned)f2h(a1) << 16);
    *(unsigned*)(aggb + ((size_t)h * N_NODES + n) * 512 + cc) = ov;
  }
}

// ---------------- layer 3 reduce: head-sum + elu + L2-normalize ----------------
__global__ __launch_bounds__(256) void reduce3(const unsigned short* __restrict__ aggb,
                                               float* __restrict__ out) {
  __shared__ float buf[4];
  const int n = blockIdx.x, tid = threadIdx.x;
  float v0 = 0.f, v1 = 0.f;
#pragma unroll
  for (int h = 0; h < 6; h++) {
    ushort2 u = *(const ushort2*)(aggb + ((size_t)h * N_NODES + n) * 512 + tid * 2);
    v0 += h2f(u.x);
    v1 += h2f(u.y);
  }
  v0 = v0 > 0.f ? v0 : __expf(v0) - 1.f;
  v1 = v1 > 0.f ? v1 : __expf(v1) - 1.f;
  float ss = block_sum(v0 * v0 + v1 * v1, buf);
  float inv = 1.f / fmaxf(sqrtf(ss), 1e-12f);
  out[(size_t)n * 512 + tid * 2] = v0 * inv;
  out[(size_t)n * 512 + tid * 2 + 1] = v1 * inv;
}

extern "C" void kernel_launch(void* const* d_in, const int* in_sizes, int n_in,
                              void* d_out, int out_size, void* d_ws, size_t ws_size,
                              hipStream_t stream) {
  (void)in_sizes; (void)n_in; (void)out_size; (void)ws_size;
  const float* x   = (const float*)d_in[0];  // [4096, 2048]
  const float* adj = (const float*)d_in[1];  // [4096, 4096]
  const float* W1  = (const float*)d_in[2];  // [4, 2048, 256]
  const float* a1  = (const float*)d_in[3];  // [4, 512]
  const float* W2  = (const float*)d_in[4];  // [4, 1024, 256]
  const float* a2  = (const float*)d_in[5];  // [4, 512]
  const float* W3  = (const float*)d_in[6];  // [6, 1024, 512]
  const float* a3  = (const float*)d_in[7];  // [6, 1024]
  float* out = (float*)d_out;                // [4096, 512]

  // workspace layout (~75 MB peak)
  char* ws = (char*)d_ws;
  size_t off = 0;
  auto alloc = [&](size_t bytes) {
    void* p = ws + off;
    off += (bytes + 255) & ~(size_t)255;
    return p;
  };
  int* nbr_cnt = (int*)alloc((size_t)N_NODES * 4);
  int* nbr_idx = (int*)alloc((size_t)N_NODES * MAXNB * 4);               // 1.6 MB
  float* fbuf = (float*)alloc((size_t)28 * N_NODES * 4);
  unsigned short* Wt = (unsigned short*)alloc((size_t)6 * 1024 * 512 * 2);  // 6.3 MB
  unsigned short* Areg = (unsigned short*)alloc((size_t)N_NODES * 2048 * 2);  // 16.8 MB
  unsigned short* Whb = (unsigned short*)alloc((size_t)N_NODES * 3072 * 2);   // 25.2 MB
  unsigned short* aggb = (unsigned short*)alloc((size_t)6 * N_NODES * 512 * 2);  // 25.2 MB

  // overlays:
  //  xh      = Areg (16.8 MB, dead after gemm1)
  //  hh      = Areg second half (written by fgather12, read by gemm2/gemm3)
  //  packed3 = Wt..Areg (18.9 MB <= 23.1 MB; both dead after gemm3; attw3 only
  //            reads fbuf/nbr_idx which precede Wt)
  unsigned short* xh = Areg;
  unsigned short* hh = Areg + (size_t)N_NODES * 1024;
  int2* packed3 = (int2*)Wt;

  float* f1_1 = fbuf;
  float* f2_1 = fbuf + 4 * N_NODES;
  float* f1_2 = fbuf + 8 * N_NODES;
  float* f2_2 = fbuf + 12 * N_NODES;
  float* f1_3 = fbuf + 16 * N_NODES;
  float* f2_3 = fbuf + 22 * N_NODES;

  build_csr<<<N_NODES, 256, 0, stream>>>(adj, nbr_cnt, nbr_idx, fbuf);

  // ---- layer 1: A = x (K=2048), Ntot = 1024, D = 256 ----
  convert_h<<<(N_NODES * 2048 / 4 + 255) / 256, 256, 0, stream>>>(
      x, xh, N_NODES * 2048 / 4);
  convert_w<<<dim3(2048 / 32, 256 / 32, 4), 256, 0, stream>>>(W1, Wt, 2048, 256);
  gemm_mfma<<<dim3(N_NODES / BM, 1024 / BN), 256, 0, stream>>>(
      xh, Wt, Whb, f1_1, f2_1, a1, 2048, 1024, 256);
  fgather12<<<4 * (N_NODES / 16), 256, 0, stream>>>(Whb, f1_1, f2_1, nbr_cnt,
                                                    nbr_idx, hh);

  // ---- layer 2: A = h (K=1024), Ntot = 1024, D = 256 ----
  convert_w<<<dim3(1024 / 32, 256 / 32, 4), 256, 0, stream>>>(W2, Wt, 1024, 256);
  gemm_mfma<<<dim3(N_NODES / BM, 1024 / BN), 256, 0, stream>>>(
      hh, Wt, Whb, f1_2, f2_2, a2, 1024, 1024, 256);
  fgather12<<<4 * (N_NODES / 16), 256, 0, stream>>>(Whb, f1_2, f2_2, nbr_cnt,
                                                    nbr_idx, hh);

  // ---- layer 3: A = h (K=1024), Ntot = 3072, D = 512 ----
  convert_w<<<dim3(1024 / 32, 512 / 32, 6), 256, 0, stream>>>(W3, Wt, 1024, 512);
  gemm_mfma<<<dim3(N_NODES / BM, 3072 / BN), 256, 0, stream>>>(
      hh, Wt, Whb, f1_3, f2_3, a3, 1024, 3072, 512);
  attw<<<N_NODES * 6 / 4, 256, 0, stream>>>(f1_3, f2_3, nbr_cnt, nbr_idx,
                                            packed3, 6, 1.f / 6.f, 6144);
  gather3<<<24 * (N_NODES / 16), 256, 0, stream>>>(Whb, packed3, nbr_cnt, aggb);
  reduce3<<<N_NODES, 256, 0, stream>>>(aggb, out);
}

// Round 11
// 393.109 us; speedup vs baseline: 1.0252x; 1.0054x over previous
//
#include <hip/hip_runtime.h>
#include <math.h>

// GAT, N=4096, ~1% adjacency. fp16 end-to-end (R9). R13: LDS-staged packed
// lists. R15: v_fma_mix_f32 + x8 unroll (gather3 57.5us plateau, R16 null).
// R18/19: attw fused into gather12, zero_f into build_csr (395.2us).
// R20: R17's 8-wave GEMM was the WRONG lever -- barrier is block-wide, so more
// waves in one block still all drain together; the m114 overlap mechanism is
// INDEPENDENT BLOCKS per CU (gemm1/2 had exactly 1 block/CU). GEMM templated
// on BN: BN=64 for layers 1/2 (grid 512 = 2 blocks/CU, LDS 24KB, acc[4][2],
// same swizzle) so block B computes while block A sits in its vmcnt+barrier
// drain. gemm3 keeps the verified BN=128 path (768 blocks = 3/CU already).

#define N_NODES 4096
#define MAXNB 96
#define BM 128
#define BK 32

typedef _Float16 f16x8 __attribute__((ext_vector_type(8)));
typedef float f32x4 __attribute__((ext_vector_type(4)));

#define GLL(gp, lp)                                                     \
  __builtin_amdgcn_global_load_lds(                                     \
      (const __attribute__((address_space(1))) void*)(gp),              \
      (__attribute__((address_space(3))) void*)(lp), 16, 0, 0)

// ---------------- fp16 helpers ----------------
union U16 {
  unsigned short u;
  _Float16 h;
};
__device__ __forceinline__ float h2f(unsigned short u) {
  U16 x;
  x.u = u;
  return (float)x.h;
}
__device__ __forceinline__ unsigned short f2h(float f) {
  U16 x;
  x.h = (_Float16)f;  // RNE
  return x.u;
}

// a += w * f16(lo/hi half of v) in ONE VALU op (VOP3P mixed-precision fma).
__device__ __forceinline__ void fmix_lo(float& a, float w, unsigned v) {
  asm("v_fma_mix_f32 %0, %1, %2, %0 op_sel:[0,0,0] op_sel_hi:[0,1,0]"
      : "+v"(a)
      : "v"(w), "v"(v));
}
__device__ __forceinline__ void fmix_hi(float& a, float w, unsigned v) {
  asm("v_fma_mix_f32 %0, %1, %2, %0 op_sel:[0,1,0] op_sel_hi:[0,1,0]"
      : "+v"(a)
      : "v"(w), "v"(v));
}

// ---------------- reduction helpers ----------------
__device__ __forceinline__ float wave_sum(float v) {
#pragma unroll
  for (int o = 32; o > 0; o >>= 1) v += __shfl_xor(v, o);
  return v;
}
__device__ __forceinline__ float wave_max(float v) {
#pragma unroll
  for (int o = 32; o > 0; o >>= 1) v = fmaxf(v, __shfl_xor(v, o));
  return v;
}
__device__ __forceinline__ float block_sum(float v, float* buf) {
  v = wave_sum(v);
  __syncthreads();
  if ((threadIdx.x & 63) == 0) buf[threadIdx.x >> 6] = v;
  __syncthreads();
  return buf[0] + buf[1] + buf[2] + buf[3];
}

// ---------------- CSR build (+ fused fbuf zero) ----------------
__global__ __launch_bounds__(256) void build_csr(const float* __restrict__ adj,
                                                 int* __restrict__ cnt,
                                                 int* __restrict__ idx,
                                                 float* __restrict__ fbuf) {
  __shared__ int c;
  if (threadIdx.x == 0) c = 0;
  if (threadIdx.x < 28) fbuf[threadIdx.x * N_NODES + blockIdx.x] = 0.f;
  __syncthreads();
  const int row = blockIdx.x;
  const float* arow = adj + (size_t)row * N_NODES;
  for (int b = 0; b < N_NODES; b += 256) {
    float v = arow[b + threadIdx.x];
    if (v > 0.f) {
      int p = atomicAdd(&c, 1);
      if (p < MAXNB) idx[row * MAXNB + p] = b + threadIdx.x;
    }
  }
  __syncthreads();
  if (threadIdx.x == 0) cnt[row] = c < MAXNB ? c : MAXNB;
}

// ---------------- elementwise fp32 -> fp16 ----------------
__global__ __launch_bounds__(256) void convert_h(const float* __restrict__ in,
                                                 unsigned short* __restrict__ oh,
                                                 int n4) {
  int i = blockIdx.x * 256 + threadIdx.x;
  if (i >= n4) return;
  float4 v = ((const float4*)in)[i];
  ushort4 h;
  h.x = f2h(v.x);
  h.y = f2h(v.y);
  h.z = f2h(v.z);
  h.w = f2h(v.w);
  ((ushort4*)oh)[i] = h;
}

// ---------------- W [H][K][D] fp32 -> Bt [H*D][K] fp16 ----------------
__global__ __launch_bounds__(256) void convert_w(const float* __restrict__ W,
                                                 unsigned short* __restrict__ th,
                                                 int K, int D) {
  __shared__ float t[32][33];
  const int h = blockIdx.z;
  const int k0 = blockIdx.x * 32, d0 = blockIdx.y * 32;
  const int tx = threadIdx.x & 31, ty = threadIdx.x >> 5;
  const float* Wp = W + (size_t)h * K * D;
#pragma unroll
  for (int r = 0; r < 4; r++)
    t[ty + r * 8][tx] = Wp[(size_t)(k0 + ty + r * 8) * D + d0 + tx];
  __syncthreads();
#pragma unroll
  for (int r = 0; r < 4; r++) {
    int d = ty + r * 8;
    th[(size_t)(h * D + d0 + d) * K + k0 + tx] = f2h(t[tx][d]);
  }
}

// ---------------- fp16 MFMA GEMM, templated tile width ----------------
// Cb[M][Ntot] (fp16) = A[M][K] @ Bt[Ntot][K]^T. 256 thr / 4 waves (2 x 2),
// each wave 64 x (BNT/2) via 4 x NB 16x16x32 frags. Conflict-free swizzle:
// 16B chunk s holds chunk (s&3)^(((s>>2)>>1)&3) of row s>>2.
// BNT=64 -> 24KB LDS, 2+ blocks/CU (barrier-drain overlap across blocks).
template <int BNT>
__global__ __launch_bounds__(256) void gemm_t(
    const unsigned short* __restrict__ A, const unsigned short* __restrict__ B,
    unsigned short* __restrict__ Cb, float* __restrict__ f1,
    float* __restrict__ f2, const float* __restrict__ af, int K, int Ntot,
    int D) {
  constexpr int NB = BNT / 32;  // B fragments per wave
  __shared__ unsigned short ldsA[2][BM * BK];
  __shared__ unsigned short ldsB[2][BNT * BK];

  const int tid = threadIdx.x;
  const int w = tid >> 6, lane = tid & 63;
  const int wm = w >> 1, wn = w & 1;
  const int quad = lane >> 4, l16 = lane & 15;
  const int m0 = blockIdx.x * BM, n0 = blockIdx.y * BNT;

  const int s0 = tid, s1 = tid + 256;
  const int rA0 = s0 >> 2, qA0 = (s0 & 3) ^ ((rA0 >> 1) & 3);
  const int rA1 = s1 >> 2, qA1 = (s1 & 3) ^ ((rA1 >> 1) & 3);
  const size_t offA0 = (size_t)(m0 + rA0) * K + qA0 * 8;
  const size_t offA1 = (size_t)(m0 + rA1) * K + qA1 * 8;
  const size_t offB0 = (size_t)(n0 + rA0) * K + qA0 * 8;  // rows 0..63 when BNT=64
  size_t offB1 = 0;
  if constexpr (BNT == 128) offB1 = (size_t)(n0 + rA1) * K + qA1 * 8;

  auto stage = [&](int b, int k0) {
    GLL(A + offA0 + k0, &ldsA[b][s0 * 8]);
    GLL(A + offA1 + k0, &ldsA[b][s1 * 8]);
    GLL(B + offB0 + k0, &ldsB[b][s0 * 8]);
    if constexpr (BNT == 128) GLL(B + offB1 + k0, &ldsB[b][s1 * 8]);
  };

  f32x4 acc[4][NB];
#pragma unroll
  for (int i = 0; i < 4; i++)
#pragma unroll
    for (int j = 0; j < NB; j++) acc[i][j] = (f32x4){0.f, 0.f, 0.f, 0.f};

  // fragment read: row r wants chunk `quad` -> stored at quad^((r>>1)&3)
  int posA[4], posB[NB];
#pragma unroll
  for (int i = 0; i < 4; i++) {
    int ra = wm * 64 + i * 16 + l16;
    posA[i] = (ra * 4 + (quad ^ ((ra >> 1) & 3))) * 8;
  }
#pragma unroll
  for (int j = 0; j < NB; j++) {
    int rb = wn * (BNT / 2) + j * 16 + l16;
    posB[j] = (rb * 4 + (quad ^ ((rb >> 1) & 3))) * 8;
  }

  const int KT = K / BK;
  stage(0, 0);
  for (int kt = 0; kt < KT; kt++) {
    const int cur = kt & 1;
    __syncthreads();
    if (kt + 1 < KT) stage(cur ^ 1, (kt + 1) * BK);

    f16x8 fa[4], fb[NB];
#pragma unroll
    for (int i = 0; i < 4; i++) fa[i] = *(const f16x8*)&ldsA[cur][posA[i]];
#pragma unroll
    for (int j = 0; j < NB; j++) fb[j] = *(const f16x8*)&ldsB[cur][posB[j]];
#pragma unroll
    for (int i = 0; i < 4; i++)
#pragma unroll
      for (int j = 0; j < NB; j++)
        acc[i][j] = __builtin_amdgcn_mfma_f32_16x16x32_f16(fa[i], fb[j],
                                                           acc[i][j], 0, 0, 0);
  }

  // epilogue 1: fp16 C write (C/D layout: col=l16, row=quad*4+r)
  const int gm = m0 + wm * 64 + quad * 4;
  const int gn = n0 + wn * (BNT / 2) + l16;
#pragma unroll
  for (int i = 0; i < 4; i++)
#pragma unroll
    for (int j = 0; j < NB; j++) {
      unsigned short* p = Cb + (size_t)(gm + i * 16) * Ntot + gn + j * 16;
#pragma unroll
      for (int r = 0; r < 4; r++) p[(size_t)r * Ntot] = f2h(acc[i][j][r]);
    }

  // epilogue 2: exact f1/f2 from fp32 acc (block spans one head: BNT | D)
  const int h = n0 / D;
  const int d0 = (n0 % D) + wn * (BNT / 2) + l16;
  float a1v[NB], a2v[NB];
#pragma unroll
  for (int j = 0; j < NB; j++) {
    a1v[j] = af[h * 2 * D + d0 + j * 16];
    a2v[j] = af[h * 2 * D + D + d0 + j * 16];
  }
#pragma unroll
  for (int i = 0; i < 4; i++)
#pragma unroll
    for (int r = 0; r < 4; r++) {
      float s1 = 0.f, s2 = 0.f;
#pragma unroll
      for (int j = 0; j < NB; j++) {
        s1 += acc[i][j][r] * a1v[j];
        s2 += acc[i][j][r] * a2v[j];
      }
#pragma unroll
      for (int m = 1; m < 16; m <<= 1) {
        s1 += __shfl_xor(s1, m);
        s2 += __shfl_xor(s2, m);
      }
      if (l16 == 0) {
        int row = gm + i * 16 + r;
        atomicAdd(&f1[h * N_NODES + row], s1);
        atomicAdd(&f2[h * N_NODES + row], s2);
      }
    }
}

// ---------------- attention weights (layer 3 only): 1 wave per (node, head) ----------------
// Writes packed {byteoff = nb*rowbytes, weight} int2 lists, zero-padded to the
// FULL MAXNB (pad entries {0, 0.f}) so gathers may over-read safely.
__global__ __launch_bounds__(256) void attw(const float* __restrict__ f1,
                                            const float* __restrict__ f2,
                                            const int* __restrict__ cnt,
                                            const int* __restrict__ idxs,
                                            int2* __restrict__ packed, int H,
                                            float scale, int rowbytes) {
  const int wid = blockIdx.x * 4 + (threadIdx.x >> 6);
  const int lane = threadIdx.x & 63;
  const int n = wid / H, h = wid - n * H;
  const int c = cnt[n];
  const float f1v = f1[h * N_NODES + n];
  int nb0 = 0, nb1 = 0;
  float e0 = -3.0e38f, e1 = -3.0e38f;
  if (lane < c) {
    nb0 = idxs[n * MAXNB + lane];
    float s = f1v + f2[h * N_NODES + nb0];
    e0 = s >= 0.f ? s : 0.2f * s;
  }
  const int j1 = lane + 64;
  if (j1 < c) {
    nb1 = idxs[n * MAXNB + j1];
    float s = f1v + f2[h * N_NODES + nb1];
    e1 = s >= 0.f ? s : 0.2f * s;
  }
  float m = wave_max(fmaxf(e0, e1));
  float w0 = (lane < c) ? __expf(e0 - m) : 0.f;
  float w1 = (j1 < c) ? __expf(e1 - m) : 0.f;
  float inv = scale / wave_sum(w0 + w1);
  int2* pk = packed + (size_t)(h * N_NODES + n) * MAXNB;
  pk[lane] = make_int2(nb0 * rowbytes, __float_as_int(w0 * inv));
  if (j1 < MAXNB) pk[j1] = make_int2(nb1 * rowbytes, __float_as_int(w1 * inv));
}

// ---------------- layers 1&2 FUSED attw+gather: 4 tiles x 256 cols ----------------
// Block = 16 nodes (4 per wave). Phase 1: each wave computes softmax weights
// for its 4 nodes (idx coalesced from global, f2 head-slab L1-hot, shuffle
// reductions) and writes packed {byteoff, weight} lists into ITS OWN LDS rows.
// Phase 2: R15 gather inner loop (ds_read b128 + fmix). No barriers at all.
__global__ __launch_bounds__(256) void fgather12(
    const unsigned short* __restrict__ Whb, const float* __restrict__ f1,
    const float* __restrict__ f2, const int* __restrict__ cnt,
    const int* __restrict__ idxs, unsigned short* __restrict__ hh) {
  __shared__ int2 sl[16][MAXNB];  // 12 KB
  const int t = blockIdx.x & 3;  // tile == head (256 cols)
  const int g = blockIdx.x >> 2;
  const int tid = threadIdx.x, w = tid >> 6, lane = tid & 63;
  const int nbase = g * 16 + w * 4;
  const int4 cv = *(const int4*)(cnt + nbase);
  const int ca[4] = {cv.x, cv.y, cv.z, cv.w};
  const float* __restrict__ f1p = f1 + t * N_NODES;
  const float* __restrict__ f2p = f2 + t * N_NODES;

  // phase 1: attention weights -> LDS packed lists (wave-private rows)
#pragma unroll
  for (int k = 0; k < 4; k++) {
    const int n = nbase + k;
    const int c = ca[k];
    const float f1v = f1p[n];
    int nb0 = 0, nb1 = 0;
    float e0 = -3.0e38f, e1 = -3.0e38f;
    if (lane < c) {
      nb0 = idxs[n * MAXNB + lane];
      float s = f1v + f2p[nb0];
      e0 = s >= 0.f ? s : 0.2f * s;
    }
    const int j1 = lane + 64;
    if (j1 < c) {
      nb1 = idxs[n * MAXNB + j1];
      float s = f1v + f2p[nb1];
      e1 = s >= 0.f ? s : 0.2f * s;
    }
    float m = wave_max(fmaxf(e0, e1));
    float w0 = (lane < c) ? __expf(e0 - m) : 0.f;
    float w1 = (j1 < c) ? __expf(e1 - m) : 0.f;
    float inv = 1.f / wave_sum(w0 + w1);
    sl[w * 4 + k][lane] = make_int2(nb0 * 2048, __float_as_int(w0 * inv));
    if (lane < MAXNB - 64)
      sl[w * 4 + k][j1] = make_int2(nb1 * 2048, __float_as_int(w1 * inv));
  }

  // phase 2: gather
  const char* wb = (const char*)Whb;
  const unsigned colb = (unsigned)(t * 256 + lane * 4) * 2u;  // 8 B per lane
#pragma unroll
  for (int k = 0; k < 4; k++) {
    const int n = nbase + k;
    const int c4 = (ca[k] + 3) & ~3;
    const int4* __restrict__ sb = (const int4*)&sl[w * 4 + k][0];
    float a0 = 0.f, a1 = 0.f, a2 = 0.f, a3 = 0.f;
    for (int j = 0; j < c4; j += 4) {
      int4 e0 = sb[j >> 1];
      int4 e1 = sb[(j >> 1) + 1];
      uint2 v0 = *(const uint2*)(wb + (unsigned)e0.x + colb);
      uint2 v1 = *(const uint2*)(wb + (unsigned)e0.z + colb);
      uint2 v2 = *(const uint2*)(wb + (unsigned)e1.x + colb);
      uint2 v3 = *(const uint2*)(wb + (unsigned)e1.z + colb);
      float w0 = __int_as_float(e0.y), w1 = __int_as_float(e0.w);
      float w2 = __int_as_float(e1.y), w3 = __int_as_float(e1.w);
      fmix_lo(a0, w0, v0.x); fmix_hi(a1, w0, v0.x);
      fmix_lo(a2, w0, v0.y); fmix_hi(a3, w0, v0.y);
      fmix_lo(a0, w1, v1.x); fmix_hi(a1, w1, v1.x);
      fmix_lo(a2, w1, v1.y); fmix_hi(a3, w1, v1.y);
      fmix_lo(a0, w2, v2.x); fmix_hi(a1, w2, v2.x);
      fmix_lo(a2, w2, v2.y); fmix_hi(a3, w2, v2.y);
      fmix_lo(a0, w3, v3.x); fmix_hi(a1, w3, v3.x);
      fmix_lo(a2, w3, v3.y); fmix_hi(a3, w3, v3.y);
    }
    float o[4] = {a0, a1, a2, a3};
    unsigned short oh[4];
#pragma unroll
    for (int s = 0; s < 4; s++) {
      float v = o[s];
      v = v > 0.f ? v : __expf(v) - 1.f;  // elu (per-head)
      v = v > 0.f ? v : __expf(v) - 1.f;  // elu (post-concat)
      oh[s] = f2h(v);
    }
    uint2 ov;
    ov.x = (unsigned)oh[0] | ((unsigned)oh[1] << 16);
    ov.y = (unsigned)oh[2] | ((unsigned)oh[3] << 16);
    *(uint2*)(hh + (size_t)n * 1024 + t * 256 + lane * 4) = ov;
  }
}

// ---------------- layer 3 gather: 24 tiles x 128 cols (XCD-balanced) ----------------
// Full wave per node, 4 B/lane, unrolled x8 (8 loads in flight per wave).
__global__ __launch_bounds__(256) void gather3(
    const unsigned short* __restrict__ Whb, const int2* __restrict__ packed,
    const int* __restrict__ cnt, unsigned short* __restrict__ aggb) {
  __shared__ int4 sl[16][MAXNB / 2];  // 12 KB
  const int t = blockIdx.x % 24;
  const int g = blockIdx.x / 24;
  const int tid = threadIdx.x, w = tid >> 6, lane = tid & 63;
  const int h = t >> 2;  // 4 tiles per head (D=512)
  const int nbase = g * 16;
  const char* src = (const char*)(packed + (size_t)(h * N_NODES + nbase) * MAXNB);
#pragma unroll
  for (int p = 0; p < 3; p++)
    GLL(src + p * 4096 + tid * 16, (char*)sl + p * 4096 + tid * 16);

  const int nb0 = nbase + w * 4;
  const int4 cv = *(const int4*)(cnt + nb0);
  const int ca[4] = {cv.x, cv.y, cv.z, cv.w};
  const char* wb = (const char*)Whb;
  const unsigned colb = (unsigned)(t * 128 + lane * 2) * 2u;  // 4 B per lane
  const int cc = t * 128 - h * 512 + lane * 2;                // col within head
  __syncthreads();

#pragma unroll
  for (int k = 0; k < 4; k++) {
    const int n = nb0 + k;
    const int c8 = (ca[k] + 7) & ~7;
    const int4* __restrict__ sb = sl[w * 4 + k];
    float a0 = 0.f, a1 = 0.f;
    for (int j = 0; j < c8; j += 8) {
      int4 e01 = sb[j >> 1];
      int4 e23 = sb[(j >> 1) + 1];
      int4 e45 = sb[(j >> 1) + 2];
      int4 e67 = sb[(j >> 1) + 3];
      unsigned v0 = *(const unsigned*)(wb + (unsigned)e01.x + colb);
      unsigned v1 = *(const unsigned*)(wb + (unsigned)e01.z + colb);
      unsigned v2 = *(const unsigned*)(wb + (unsigned)e23.x + colb);
      unsigned v3 = *(const unsigned*)(wb + (unsigned)e23.z + colb);
      unsigned v4 = *(const unsigned*)(wb + (unsigned)e45.x + colb);
      unsigned v5 = *(const unsigned*)(wb + (unsigned)e45.z + colb);
      unsigned v6 = *(const unsigned*)(wb + (unsigned)e67.x + colb);
      unsigned v7 = *(const unsigned*)(wb + (unsigned)e67.z + colb);
      float w0 = __int_as_float(e01.y), w1 = __int_as_float(e01.w);
      float w2 = __int_as_float(e23.y), w3 = __int_as_float(e23.w);
      float w4 = __int_as_float(e45.y), w5 = __int_as_float(e45.w);
      float w6 = __int_as_float(e67.y), w7 = __int_as_float(e67.w);
      fmix_lo(a0, w0, v0); fmix_hi(a1, w0, v0);
      fmix_lo(a0, w1, v1); fmix_hi(a1, w1, v1);
      fmix_lo(a0, w2, v2); fmix_hi(a1, w2, v2);
      fmix_lo(a0, w3, v3); fmix_hi(a1, w3, v3);
      fmix_lo(a0, w4, v4); fmix_hi(a1, w4, v4);
      fmix_lo(a0, w5, v5); fmix_hi(a1, w5, v5);
      fmix_lo(a0, w6, v6); fmix_hi(a1, w6, v6);
      fmix_lo(a0, w7, v7); fmix_hi(a1, w7, v7);
    }
    unsigned ov = (unsigned)f2h(a0) | ((unsigned)f2h(a1) << 16);
    *(unsigned*)(aggb + ((size_t)h * N_NODES + n) * 512 + cc) = ov;
  }
}

// ---------------- layer 3 reduce: head-sum + elu + L2-normalize ----------------
__global__ __launch_bounds__(256) void reduce3(const unsigned short* __restrict__ aggb,
                                               float* __restrict__ out) {
  __shared__ float buf[4];
  const int n = blockIdx.x, tid = threadIdx.x;
  float v0 = 0.f, v1 = 0.f;
#pragma unroll
  for (int h = 0; h < 6; h++) {
    ushort2 u = *(const ushort2*)(aggb + ((size_t)h * N_NODES + n) * 512 + tid * 2);
    v0 += h2f(u.x);
    v1 += h2f(u.y);
  }
  v0 = v0 > 0.f ? v0 : __expf(v0) - 1.f;
  v1 = v1 > 0.f ? v1 : __expf(v1) - 1.f;
  float ss = block_sum(v0 * v0 + v1 * v1, buf);
  float inv = 1.f / fmaxf(sqrtf(ss), 1e-12f);
  out[(size_t)n * 512 + tid * 2] = v0 * inv;
  out[(size_t)n * 512 + tid * 2 + 1] = v1 * inv;
}

extern "C" void kernel_launch(void* const* d_in, const int* in_sizes, int n_in,
                              void* d_out, int out_size, void* d_ws, size_t ws_size,
                              hipStream_t stream) {
  (void)in_sizes; (void)n_in; (void)out_size; (void)ws_size;
  const float* x   = (const float*)d_in[0];  // [4096, 2048]
  const float* adj = (const float*)d_in[1];  // [4096, 4096]
  const float* W1  = (const float*)d_in[2];  // [4, 2048, 256]
  const float* a1  = (const float*)d_in[3];  // [4, 512]
  const float* W2  = (const float*)d_in[4];  // [4, 1024, 256]
  const float* a2  = (const float*)d_in[5];  // [4, 512]
  const float* W3  = (const float*)d_in[6];  // [6, 1024, 512]
  const float* a3  = (const float*)d_in[7];  // [6, 1024]
  float* out = (float*)d_out;                // [4096, 512]

  // workspace layout (~75 MB peak)
  char* ws = (char*)d_ws;
  size_t off = 0;
  auto alloc = [&](size_t bytes) {
    void* p = ws + off;
    off += (bytes + 255) & ~(size_t)255;
    return p;
  };
  int* nbr_cnt = (int*)alloc((size_t)N_NODES * 4);
  int* nbr_idx = (int*)alloc((size_t)N_NODES * MAXNB * 4);               // 1.6 MB
  float* fbuf = (float*)alloc((size_t)28 * N_NODES * 4);
  unsigned short* Wt = (unsigned short*)alloc((size_t)6 * 1024 * 512 * 2);  // 6.3 MB
  unsigned short* Areg = (unsigned short*)alloc((size_t)N_NODES * 2048 * 2);  // 16.8 MB
  unsigned short* Whb = (unsigned short*)alloc((size_t)N_NODES * 3072 * 2);   // 25.2 MB
  unsigned short* aggb = (unsigned short*)alloc((size_t)6 * N_NODES * 512 * 2);  // 25.2 MB

  // overlays:
  //  xh      = Areg (16.8 MB, dead after gemm1)
  //  hh      = Areg second half (written by fgather12, read by gemm2/gemm3)
  //  packed3 = Wt..Areg (18.9 MB <= 23.1 MB; both dead after gemm3; attw3 only
  //            reads fbuf/nbr_idx which precede Wt)
  unsigned short* xh = Areg;
  unsigned short* hh = Areg + (size_t)N_NODES * 1024;
  int2* packed3 = (int2*)Wt;

  float* f1_1 = fbuf;
  float* f2_1 = fbuf + 4 * N_NODES;
  float* f1_2 = fbuf + 8 * N_NODES;
  float* f2_2 = fbuf + 12 * N_NODES;
  float* f1_3 = fbuf + 16 * N_NODES;
  float* f2_3 = fbuf + 22 * N_NODES;

  build_csr<<<N_NODES, 256, 0, stream>>>(adj, nbr_cnt, nbr_idx, fbuf);

  // ---- layer 1: A = x (K=2048), Ntot = 1024, D = 256 ----
  convert_h<<<(N_NODES * 2048 / 4 + 255) / 256, 256, 0, stream>>>(
      x, xh, N_NODES * 2048 / 4);
  convert_w<<<dim3(2048 / 32, 256 / 32, 4), 256, 0, stream>>>(W1, Wt, 2048, 256);
  gemm_t<64><<<dim3(N_NODES / BM, 1024 / 64), 256, 0, stream>>>(
      xh, Wt, Whb, f1_1, f2_1, a1, 2048, 1024, 256);
  fgather12<<<4 * (N_NODES / 16), 256, 0, stream>>>(Whb, f1_1, f2_1, nbr_cnt,
                                                    nbr_idx, hh);

  // ---- layer 2: A = h (K=1024), Ntot = 1024, D = 256 ----
  convert_w<<<dim3(1024 / 32, 256 / 32, 4), 256, 0, stream>>>(W2, Wt, 1024, 256);
  gemm_t<64><<<dim3(N_NODES / BM, 1024 / 64), 256, 0, stream>>>(
      hh, Wt, Whb, f1_2, f2_2, a2, 1024, 1024, 256);
  fgather12<<<4 * (N_NODES / 16), 256, 0, stream>>>(Whb, f1_2, f2_2, nbr_cnt,
                                                    nbr_idx, hh);

  // ---- layer 3: A = h (K=1024), Ntot = 3072, D = 512 ----
  convert_w<<<dim3(1024 / 32, 512 / 32, 6), 256, 0, stream>>>(W3, Wt, 1024, 512);
  gemm_t<128><<<dim3(N_NODES / BM, 3072 / 128), 256, 0, stream>>>(
      hh, Wt, Whb, f1_3, f2_3, a3, 1024, 3072, 512);
  attw<<<N_NODES * 6 / 4, 256, 0, stream>>>(f1_3, f2_3, nbr_cnt, nbr_idx,
                                            packed3, 6, 1.f / 6.f, 6144);
  gather3<<<24 * (N_NODES / 16), 256, 0, stream>>>(Whb, packed3, nbr_cnt, aggb);
  reduce3<<<N_NODES, 256, 0, stream>>>(aggb, out);
}